// Round 4
// baseline (322.196 us; speedup 1.0000x reference)
//
#include <hip/hip_runtime.h>

// MHA forward, MI355X gfx950.
// B=2, L=2048, D=1024, H=16, DK=64. Outputs: y [B,L,D] f32 then A [B,H,L,L] f32.
// fp16 MFMA, f32 accumulate. Two-pass causal softmax with fixed-offset
// normalization; S^T layout (swapped mfma operands) for float4 A-stores.
// Round 4: nontemporal A/zero stores (keep K/V L2-resident), 2-wave blocks
// grid 1024 (16 waves/CU), SC folded into Wq, V-issue between QK and softmax.

typedef _Float16 h8 __attribute__((ext_vector_type(8)));
typedef _Float16 h4 __attribute__((ext_vector_type(4)));
typedef float f4 __attribute__((ext_vector_type(4)));

#define L_SEQ 2048
#define NH 16
#define DKH 64
#define DM 1024

static __device__ __forceinline__ void gload16(const void* g, void* l) {
  __builtin_amdgcn_global_load_lds(
      (const __attribute__((address_space(1))) char*)g,
      (__attribute__((address_space(3))) char*)l, 16, 0, 0);
}

// ---------------- cast f32 -> f16 (vectorized) ----------------
__global__ __launch_bounds__(256) void k_cast(const float* __restrict__ in,
                                              _Float16* __restrict__ out, int n4) {
  int i = blockIdx.x * 256 + threadIdx.x;
  if (i >= n4) return;
  f4 v = ((const f4*)in)[i];
  h4 o = {(_Float16)v[0], (_Float16)v[1], (_Float16)v[2], (_Float16)v[3]};
  ((h4*)out)[i] = o;
}

// ------------- transpose+cast weights: W[k][n] f32 -> Wt[n][k] f16 -------------
// z==0 (Wq) additionally folds in SC = log2(e)/sqrt(dk), so QK^T comes out in
// the exp2 domain with no per-element scaling in the attention kernel.
__global__ __launch_bounds__(256) void k_wt(const float* w0, const float* w1,
                                            const float* w2, const float* w3,
                                            _Float16* o0, _Float16* o1,
                                            _Float16* o2, _Float16* o3) {
  __shared__ _Float16 tile[64][65];
  const float* W;
  _Float16* O;
  switch (blockIdx.z) {
    case 0: W = w0; O = o0; break;
    case 1: W = w1; O = o1; break;
    case 2: W = w2; O = o2; break;
    default: W = w3; O = o3; break;
  }
  const float scl = (blockIdx.z == 0) ? 0.18033688011112042f : 1.0f;
  int n0 = blockIdx.x * 64, k0 = blockIdx.y * 64;
  int t = threadIdx.x, c = t & 63, r0 = (t >> 6) * 16;
  for (int i = 0; i < 16; ++i)
    tile[r0 + i][c] = (_Float16)(W[(size_t)(k0 + r0 + i) * DM + n0 + c] * scl);
  __syncthreads();
  for (int i = 0; i < 16; ++i)
    O[(size_t)(n0 + r0 + i) * DM + k0 + c] = tile[c][r0 + i];
}

// ------------- transpose V: [bh][L][64] -> [bh][64][L] -------------
__global__ __launch_bounds__(256) void k_vt(const _Float16* __restrict__ Vb,
                                            _Float16* __restrict__ Vt) {
  __shared__ _Float16 tile[64][65];
  int blk = blockIdx.x, bh = blk >> 5, l0 = (blk & 31) * 64;
  const _Float16* src = Vb + (size_t)bh * L_SEQ * DKH;
  _Float16* dst = Vt + (size_t)bh * DKH * L_SEQ;
  int t = threadIdx.x, c = t & 63, r0 = (t >> 6) * 16;
  for (int i = 0; i < 16; ++i)
    tile[r0 + i][c] = src[(size_t)(l0 + r0 + i) * DKH + c];
  __syncthreads();
  for (int i = 0; i < 16; ++i)
    dst[(size_t)(r0 + i) * L_SEQ + l0 + c] = tile[c][r0 + i];
}

// ------------- GEMM: C[4096x1024] = A[4096x1024] * Bt[1024x1024]^T -------------
__global__ __launch_bounds__(256) void k_gemm(const _Float16* __restrict__ A,
                                              const _Float16* __restrict__ B0,
                                              const _Float16* __restrict__ B1,
                                              const _Float16* __restrict__ B2,
                                              void* o0, void* o1, void* o2,
                                              int mode) {
  const _Float16* Bt = blockIdx.z == 0 ? B0 : (blockIdx.z == 1 ? B1 : B2);
  void* out = blockIdx.z == 0 ? o0 : (blockIdx.z == 1 ? o1 : o2);
  __shared__ __align__(16) _Float16 lA[128 * 32];
  __shared__ __align__(16) _Float16 lB[128 * 32];
  int t = threadIdx.x, lane = t & 63, w = t >> 6;
  int l15 = lane & 15, g = lane >> 4;
  int wr = w >> 1, wc = w & 1;
  int m0 = blockIdx.x * 128, n0 = blockIdx.y * 128;
  f4 zed = {0.f, 0.f, 0.f, 0.f};
  f4 acc[4][4];
  for (int i = 0; i < 4; ++i)
    for (int j = 0; j < 4; ++j) acc[i][j] = zed;

  int row = t >> 2, colh = (t & 3) * 8;
  const _Float16* ga = A + (size_t)(m0 + row) * DM + colh;
  const _Float16* gb = Bt + (size_t)(n0 + row) * DM + colh;
  _Float16* la0 = &lA[row * 32 + colh];
  _Float16* la1 = &lA[2048 + row * 32 + colh];
  _Float16* lb0 = &lB[row * 32 + colh];
  _Float16* lb1 = &lB[2048 + row * 32 + colh];

  for (int k0 = 0; k0 < DM; k0 += 32) {
    __syncthreads();
    gload16(ga + k0, la0);
    gload16(ga + (size_t)64 * DM + k0, la1);
    gload16(gb + k0, lb0);
    gload16(gb + (size_t)64 * DM + k0, lb1);
    __syncthreads();
    h8 af[4], bfr[4];
#pragma unroll
    for (int mr = 0; mr < 4; ++mr)
      af[mr] = *(const h8*)&lA[(wr * 64 + mr * 16 + l15) * 32 + g * 8];
#pragma unroll
    for (int nr = 0; nr < 4; ++nr)
      bfr[nr] = *(const h8*)&lB[(wc * 64 + nr * 16 + l15) * 32 + g * 8];
#pragma unroll
    for (int mr = 0; mr < 4; ++mr)
#pragma unroll
      for (int nr = 0; nr < 4; ++nr)
        acc[mr][nr] = __builtin_amdgcn_mfma_f32_16x16x32_f16(af[mr], bfr[nr],
                                                             acc[mr][nr], 0, 0, 0);
  }

  if (mode == 0) {
    _Float16* o = (_Float16*)out;
#pragma unroll
    for (int mr = 0; mr < 4; ++mr)
#pragma unroll
      for (int nr = 0; nr < 4; ++nr) {
        int n = n0 + wc * 64 + nr * 16 + l15;
        int h = n >> 6, dk = n & 63;
#pragma unroll
        for (int r = 0; r < 4; ++r) {
          int m = m0 + wr * 64 + mr * 16 + g * 4 + r;
          int b = m >> 11, l = m & 2047;
          o[(((size_t)b * NH + h) * L_SEQ + l) * DKH + dk] = (_Float16)acc[mr][nr][r];
        }
      }
  } else {
    float* o = (float*)out;
#pragma unroll
    for (int mr = 0; mr < 4; ++mr)
#pragma unroll
      for (int nr = 0; nr < 4; ++nr) {
        int n = n0 + wc * 64 + nr * 16 + l15;
#pragma unroll
        for (int r = 0; r < 4; ++r) {
          int m = m0 + wr * 64 + mr * 16 + g * 4 + r;
          o[(size_t)m * DM + n] = acc[mr][nr][r];
        }
      }
  }
}

// ------------- attention -------------
// Block = 2 waves; each wave owns 32 q-rows (two 16-row S^T sub-tiles a/b that
// SHARE the K fragments in QK^T and the V fragments in PV). Grid 1024 =
// 32 bh x 32 qt; bh = blk & 31 (constant XCD per head), qt = 31 - (blk >> 5)
// (heavy tiles first). 128-thread blocks + VGPR<=128 -> 8 block slots/CU
// (16 waves/CU) for latency hiding.
// Q is pre-scaled by log2(e)/8 (k_wt), so S comes out in the exp2 domain.
// A and the zero-fill use nontemporal stores so the 537MB A stream does not
// evict K/V from L2.
__global__ __launch_bounds__(128, 4) void k_attn(const _Float16* __restrict__ Qh,
                                                 const _Float16* __restrict__ Kh,
                                                 const _Float16* __restrict__ Vt,
                                                 float* __restrict__ Aout,
                                                 _Float16* __restrict__ Oh) {
  __shared__ __align__(16) _Float16 Plds[2][2][1024];  // 2KB per wave per sub-tile
  const int blk = blockIdx.x;
  const int bh = blk & 31;
  const int qt = 31 - (blk >> 5);
  const int b = bh >> 4, h = bh & 15;
  const int t = threadIdx.x, w = t >> 6, lane = t & 63;
  const int l15 = lane & 15, g = lane >> 4;
  const int q0 = qt * 64 + w * 32;  // wave's rows: q0 .. q0+31
  const int qa = q0 + l15;          // sub-tile a row (S^T layout)
  const int qb = q0 + 16 + l15;     // sub-tile b row

  const _Float16* Qp = Qh + ((size_t)bh * L_SEQ + qa) * DKH + g * 8;
  const h8 qa0 = *(const h8*)Qp;
  const h8 qa1 = *(const h8*)(Qp + 32);
  const h8 qb0 = *(const h8*)(Qp + 16 * DKH);
  const h8 qb1 = *(const h8*)(Qp + 16 * DKH + 32);
  const _Float16* Kbase = Kh + (size_t)bh * L_SEQ * DKH;
  const _Float16* Vbase = Vt + (size_t)bh * DKH * L_SEQ;
  float* Abase = Aout + (size_t)bh * L_SEQ * L_SEQ;
  char* pA = (char*)&Plds[w][0][0];
  char* pB = (char*)&Plds[w][1][0];
  const int swz = (l15 & 7) << 4;

  const int nfull = q0 >> 6;  // chunks 0..nfull-1 fully unmasked; nfull = diagonal
  f4 zed = {0.f, 0.f, 0.f, 0.f};

  // ---- pass 1: per-row l0 = sum exp2(sv), m = max(sv) ----
  float mA = -1e30f, sumA = 0.f, mB = -1e30f, sumB = 0.f;
  for (int c = 0; c < nfull; ++c) {
    const _Float16* Kp = Kbase + (size_t)(c * 64 + l15) * DKH + g * 8;
    h8 kf0[4], kf1[4];
#pragma unroll
    for (int tt = 0; tt < 4; ++tt) {
      kf0[tt] = *(const h8*)(Kp + (size_t)tt * 16 * DKH);
      kf1[tt] = *(const h8*)(Kp + (size_t)tt * 16 * DKH + 32);
    }
    f4 sa[4], sb[4];
    __builtin_amdgcn_s_setprio(1);
#pragma unroll
    for (int tt = 0; tt < 4; ++tt) {
      sa[tt] = __builtin_amdgcn_mfma_f32_16x16x32_f16(kf0[tt], qa0, zed, 0, 0, 0);
      sa[tt] = __builtin_amdgcn_mfma_f32_16x16x32_f16(kf1[tt], qa1, sa[tt], 0, 0, 0);
      sb[tt] = __builtin_amdgcn_mfma_f32_16x16x32_f16(kf0[tt], qb0, zed, 0, 0, 0);
      sb[tt] = __builtin_amdgcn_mfma_f32_16x16x32_f16(kf1[tt], qb1, sb[tt], 0, 0, 0);
    }
    __builtin_amdgcn_s_setprio(0);
#pragma unroll
    for (int tt = 0; tt < 4; ++tt)
#pragma unroll
      for (int r = 0; r < 4; ++r) {
        float va = sa[tt][r], vb = sb[tt][r];
        mA = fmaxf(mA, va);
        sumA += __builtin_amdgcn_exp2f(va);
        mB = fmaxf(mB, vb);
        sumB += __builtin_amdgcn_exp2f(vb);
      }
  }
  {  // diagonal chunk (chunk index nfull), causal-masked
    const _Float16* Kp = Kbase + (size_t)(nfull * 64 + l15) * DKH + g * 8;
    h8 kf0[4], kf1[4];
#pragma unroll
    for (int tt = 0; tt < 4; ++tt) {
      kf0[tt] = *(const h8*)(Kp + (size_t)tt * 16 * DKH);
      kf1[tt] = *(const h8*)(Kp + (size_t)tt * 16 * DKH + 32);
    }
    f4 sa[4], sb[4];
    __builtin_amdgcn_s_setprio(1);
#pragma unroll
    for (int tt = 0; tt < 4; ++tt) {
      sa[tt] = __builtin_amdgcn_mfma_f32_16x16x32_f16(kf0[tt], qa0, zed, 0, 0, 0);
      sa[tt] = __builtin_amdgcn_mfma_f32_16x16x32_f16(kf1[tt], qa1, sa[tt], 0, 0, 0);
      sb[tt] = __builtin_amdgcn_mfma_f32_16x16x32_f16(kf0[tt], qb0, zed, 0, 0, 0);
      sb[tt] = __builtin_amdgcn_mfma_f32_16x16x32_f16(kf1[tt], qb1, sb[tt], 0, 0, 0);
    }
    __builtin_amdgcn_s_setprio(0);
#pragma unroll
    for (int tt = 0; tt < 4; ++tt) {
      int kb = nfull * 64 + tt * 16 + g * 4;
#pragma unroll
      for (int r = 0; r < 4; ++r) {
        float va = (kb + r <= qa) ? sa[tt][r] : -1e30f;
        float vb = (kb + r <= qb) ? sb[tt][r] : -1e30f;
        mA = fmaxf(mA, va);
        sumA += __builtin_amdgcn_exp2f(va);  // masked -> 0
        mB = fmaxf(mB, vb);
        sumB += __builtin_amdgcn_exp2f(vb);
      }
    }
  }
  // reduce over the 4 lanes sharing each q-row (l15, +16, +32, +48)
  mA = fmaxf(mA, __shfl_xor(mA, 16, 64));
  sumA += __shfl_xor(sumA, 16, 64);
  mA = fmaxf(mA, __shfl_xor(mA, 32, 64));
  sumA += __shfl_xor(sumA, 32, 64);
  mB = fmaxf(mB, __shfl_xor(mB, 16, 64));
  sumB += __shfl_xor(sumB, 16, 64);
  mB = fmaxf(mB, __shfl_xor(mB, 32, 64));
  sumB += __shfl_xor(sumB, 32, 64);
  const float cA = fmaxf(mA - 12.f, 0.f);  // f16 guard: P = exp2(sv-c) <= 4096
  const float cB = fmaxf(mB - 12.f, 0.f);
  const float invA = __builtin_amdgcn_exp2f(cA) / sumA;
  const float invB = __builtin_amdgcn_exp2f(cB) / sumB;

  // ---- pass 2: recompute S, write A = exp2(sv-c)*inv (nt), accumulate O ----
  f4 oaccA[4], oaccB[4];
#pragma unroll
  for (int dt = 0; dt < 4; ++dt) { oaccA[dt] = zed; oaccB[dt] = zed; }

  for (int cc = 0; cc <= nfull; ++cc) {
    const _Float16* Kp = Kbase + (size_t)(cc * 64 + l15) * DKH + g * 8;
    h8 kf0[4], kf1[4];
#pragma unroll
    for (int tt = 0; tt < 4; ++tt) {
      kf0[tt] = *(const h8*)(Kp + (size_t)tt * 16 * DKH);
      kf1[tt] = *(const h8*)(Kp + (size_t)tt * 16 * DKH + 32);
    }
    f4 sa[4], sb[4];
    __builtin_amdgcn_s_setprio(1);
#pragma unroll
    for (int tt = 0; tt < 4; ++tt) {
      sa[tt] = __builtin_amdgcn_mfma_f32_16x16x32_f16(kf0[tt], qa0, zed, 0, 0, 0);
      sa[tt] = __builtin_amdgcn_mfma_f32_16x16x32_f16(kf1[tt], qa1, sa[tt], 0, 0, 0);
      sb[tt] = __builtin_amdgcn_mfma_f32_16x16x32_f16(kf0[tt], qb0, zed, 0, 0, 0);
      sb[tt] = __builtin_amdgcn_mfma_f32_16x16x32_f16(kf1[tt], qb1, sb[tt], 0, 0, 0);
    }
    __builtin_amdgcn_s_setprio(0);

    // V loads issued here: K-frags are dead (regs free) and the softmax VALU
    // block below hides the L2 latency.
    const _Float16* Vp = Vbase + (size_t)l15 * L_SEQ + cc * 64 + g * 8;
    h8 vf[8];
#pragma unroll
    for (int ks = 0; ks < 2; ++ks)
#pragma unroll
      for (int dt = 0; dt < 4; ++dt)
        vf[ks * 4 + dt] = *(const h8*)(Vp + (size_t)dt * 16 * L_SEQ + ks * 32);

    const bool dchunk = (cc == nfull);
    float* ArowA = Abase + (size_t)qa * L_SEQ + cc * 64 + g * 4;
    float* ArowB = Abase + (size_t)qb * L_SEQ + cc * 64 + g * 4;
#pragma unroll
    for (int tt = 0; tt < 4; ++tt) {
      f4 pv;
#pragma unroll
      for (int r = 0; r < 4; ++r) {
        float sv = sa[tt][r] - cA;
        if (dchunk && (cc * 64 + tt * 16 + g * 4 + r > qa)) sv = -1e30f;
        pv[r] = __builtin_amdgcn_exp2f(sv);
      }
      f4 av = {pv[0] * invA, pv[1] * invA, pv[2] * invA, pv[3] * invA};
      __builtin_nontemporal_store(av, (f4*)(ArowA + tt * 16));
      h4 ph = {(_Float16)pv[0], (_Float16)pv[1], (_Float16)pv[2], (_Float16)pv[3]};
      *(h4*)(pA + l15 * 128 + ((tt * 32 + g * 8) ^ swz)) = ph;
    }
#pragma unroll
    for (int tt = 0; tt < 4; ++tt) {
      f4 pv;
#pragma unroll
      for (int r = 0; r < 4; ++r) {
        float sv = sb[tt][r] - cB;
        if (dchunk && (cc * 64 + tt * 16 + g * 4 + r > qb)) sv = -1e30f;
        pv[r] = __builtin_amdgcn_exp2f(sv);
      }
      f4 av = {pv[0] * invB, pv[1] * invB, pv[2] * invB, pv[3] * invB};
      __builtin_nontemporal_store(av, (f4*)(ArowB + tt * 16));
      h4 ph = {(_Float16)pv[0], (_Float16)pv[1], (_Float16)pv[2], (_Float16)pv[3]};
      *(h4*)(pB + l15 * 128 + ((tt * 32 + g * 8) ^ swz)) = ph;
    }
    asm volatile("s_waitcnt lgkmcnt(0)" ::: "memory");
    __builtin_amdgcn_sched_barrier(0);
    __builtin_amdgcn_s_setprio(1);
#pragma unroll
    for (int ks = 0; ks < 2; ++ks) {
      h8 pfa = *(const h8*)(pA + l15 * 128 + ((ks * 64 + g * 16) ^ swz));
      h8 pfb = *(const h8*)(pB + l15 * 128 + ((ks * 64 + g * 16) ^ swz));
#pragma unroll
      for (int dt = 0; dt < 4; ++dt) {
        oaccA[dt] = __builtin_amdgcn_mfma_f32_16x16x32_f16(pfa, vf[ks * 4 + dt],
                                                           oaccA[dt], 0, 0, 0);
        oaccB[dt] = __builtin_amdgcn_mfma_f32_16x16x32_f16(pfb, vf[ks * 4 + dt],
                                                           oaccB[dt], 0, 0, 0);
      }
    }
    __builtin_amdgcn_s_setprio(0);
  }

  // O write (f16, [B][L][D]); O rows live at q = g*4+r (C-layout), so fetch
  // that row's scale from the lane that owns it (lane g*4+r has l15 == g*4+r).
  float scA[4], scB[4];
#pragma unroll
  for (int r = 0; r < 4; ++r) {
    scA[r] = __shfl(invA, g * 4 + r, 64);
    scB[r] = __shfl(invB, g * 4 + r, 64);
  }
#pragma unroll
  for (int dt = 0; dt < 4; ++dt)
#pragma unroll
    for (int r = 0; r < 4; ++r) {
      int qra = q0 + g * 4 + r;
      Oh[((size_t)b * L_SEQ + qra) * DM + h * DKH + dt * 16 + l15] =
          (_Float16)(oaccA[dt][r] * scA[r]);
      Oh[((size_t)b * L_SEQ + qra + 16) * DM + h * DKH + dt * 16 + l15] =
          (_Float16)(oaccB[dt][r] * scB[r]);
    }

  // zero-fill strictly-masked columns beyond the diagonal chunk (nt stores)
  const int zs = (nfull + 1) * 64;
  for (int rr = 0; rr < 32; ++rr) {
    float* p = Abase + (size_t)(q0 + rr) * L_SEQ;
    for (int cz = zs + lane * 4; cz < L_SEQ; cz += 256)
      __builtin_nontemporal_store(zed, (f4*)(p + cz));
  }
}

extern "C" void kernel_launch(void* const* d_in, const int* in_sizes, int n_in,
                              void* d_out, int out_size, void* d_ws, size_t ws_size,
                              hipStream_t stream) {
  const float* query = (const float*)d_in[0];
  // d_in[1] = causal mask (constant triu k=1) — recomputed in-kernel, unused.
  const float* Wq = (const float*)d_in[2];
  const float* Wk = (const float*)d_in[3];
  const float* Wv = (const float*)d_in[4];
  const float* Wo = (const float*)d_in[5];

  char* ws = (char*)d_ws;
  _Float16* qh  = (_Float16*)(ws);                      //  8 MB  [4096][1024]
  _Float16* Wtq = (_Float16*)(ws + (8ull  << 20));      //  2 MB  [1024][1024]
  _Float16* Wtk = (_Float16*)(ws + (10ull << 20));
  _Float16* Wtv = (_Float16*)(ws + (12ull << 20));
  _Float16* Wto = (_Float16*)(ws + (14ull << 20));
  _Float16* Qh  = (_Float16*)(ws + (16ull << 20));      //  8 MB  [bh][L][64]
  _Float16* Kh  = (_Float16*)(ws + (24ull << 20));
  _Float16* Vh  = (_Float16*)(ws + (32ull << 20));
  _Float16* Vtr = (_Float16*)(ws + (40ull << 20));      //  8 MB  [bh][64][L]
  _Float16* Oh  = (_Float16*)(ws + (48ull << 20));      //  8 MB  [4096][1024]

  float* y = (float*)d_out;
  float* Afull = y + (size_t)4194304;

  k_cast<<<4096, 256, 0, stream>>>(query, qh, 1048576);
  k_wt<<<dim3(16, 16, 4), 256, 0, stream>>>(Wq, Wk, Wv, Wo, Wtq, Wtk, Wtv, Wto);
  k_gemm<<<dim3(32, 8, 3), 256, 0, stream>>>(qh, Wtq, Wtk, Wtv, Qh, Kh, Vh, 0);
  k_vt<<<1024, 256, 0, stream>>>(Vh, Vtr);
  k_attn<<<1024, 128, 0, stream>>>(Qh, Kh, Vtr, Afull, Oh);
  k_gemm<<<dim3(32, 8, 1), 256, 0, stream>>>(Oh, Wto, Wto, Wto, y, y, y, 1);
}

// Round 5
// 305.448 us; speedup vs baseline: 1.0548x; 1.0548x over previous
//
#include <hip/hip_runtime.h>

// MHA forward, MI355X gfx950.
// B=2, L=2048, D=1024, H=16, DK=64. Outputs: y [B,L,D] f32 then A [B,H,L,L] f32.
// fp16 MFMA, f32 accumulate. Two-pass causal softmax with fixed-offset
// normalization; S^T layout (swapped mfma operands) for float4 A-stores.
// Round 5: back to 4-wave blocks (VGPR cap 256 -> no spills) + complement
// pairing (each wave owns 16 rows of tile p and 16 rows of tile 31-p ->
// constant work per wave, zero tail imbalance). Keep: nt A-stores, SC folded
// into Wq, V-issue after QK^T, setprio.

typedef _Float16 h8 __attribute__((ext_vector_type(8)));
typedef _Float16 h4 __attribute__((ext_vector_type(4)));
typedef float f4 __attribute__((ext_vector_type(4)));

#define L_SEQ 2048
#define NH 16
#define DKH 64
#define DM 1024

static __device__ __forceinline__ void gload16(const void* g, void* l) {
  __builtin_amdgcn_global_load_lds(
      (const __attribute__((address_space(1))) char*)g,
      (__attribute__((address_space(3))) char*)l, 16, 0, 0);
}

// ---------------- cast f32 -> f16 (vectorized) ----------------
__global__ __launch_bounds__(256) void k_cast(const float* __restrict__ in,
                                              _Float16* __restrict__ out, int n4) {
  int i = blockIdx.x * 256 + threadIdx.x;
  if (i >= n4) return;
  f4 v = ((const f4*)in)[i];
  h4 o = {(_Float16)v[0], (_Float16)v[1], (_Float16)v[2], (_Float16)v[3]};
  ((h4*)out)[i] = o;
}

// ------------- transpose+cast weights: W[k][n] f32 -> Wt[n][k] f16 -------------
// z==0 (Wq) additionally folds in SC = log2(e)/sqrt(dk), so QK^T comes out in
// the exp2 domain with no per-element scaling in the attention kernel.
__global__ __launch_bounds__(256) void k_wt(const float* w0, const float* w1,
                                            const float* w2, const float* w3,
                                            _Float16* o0, _Float16* o1,
                                            _Float16* o2, _Float16* o3) {
  __shared__ _Float16 tile[64][65];
  const float* W;
  _Float16* O;
  switch (blockIdx.z) {
    case 0: W = w0; O = o0; break;
    case 1: W = w1; O = o1; break;
    case 2: W = w2; O = o2; break;
    default: W = w3; O = o3; break;
  }
  const float scl = (blockIdx.z == 0) ? 0.18033688011112042f : 1.0f;
  int n0 = blockIdx.x * 64, k0 = blockIdx.y * 64;
  int t = threadIdx.x, c = t & 63, r0 = (t >> 6) * 16;
  for (int i = 0; i < 16; ++i)
    tile[r0 + i][c] = (_Float16)(W[(size_t)(k0 + r0 + i) * DM + n0 + c] * scl);
  __syncthreads();
  for (int i = 0; i < 16; ++i)
    O[(size_t)(n0 + r0 + i) * DM + k0 + c] = tile[c][r0 + i];
}

// ------------- transpose V: [bh][L][64] -> [bh][64][L] -------------
__global__ __launch_bounds__(256) void k_vt(const _Float16* __restrict__ Vb,
                                            _Float16* __restrict__ Vt) {
  __shared__ _Float16 tile[64][65];
  int blk = blockIdx.x, bh = blk >> 5, l0 = (blk & 31) * 64;
  const _Float16* src = Vb + (size_t)bh * L_SEQ * DKH;
  _Float16* dst = Vt + (size_t)bh * DKH * L_SEQ;
  int t = threadIdx.x, c = t & 63, r0 = (t >> 6) * 16;
  for (int i = 0; i < 16; ++i)
    tile[r0 + i][c] = src[(size_t)(l0 + r0 + i) * DKH + c];
  __syncthreads();
  for (int i = 0; i < 16; ++i)
    dst[(size_t)(r0 + i) * L_SEQ + l0 + c] = tile[c][r0 + i];
}

// ------------- GEMM: C[4096x1024] = A[4096x1024] * Bt[1024x1024]^T -------------
__global__ __launch_bounds__(256) void k_gemm(const _Float16* __restrict__ A,
                                              const _Float16* __restrict__ B0,
                                              const _Float16* __restrict__ B1,
                                              const _Float16* __restrict__ B2,
                                              void* o0, void* o1, void* o2,
                                              int mode) {
  const _Float16* Bt = blockIdx.z == 0 ? B0 : (blockIdx.z == 1 ? B1 : B2);
  void* out = blockIdx.z == 0 ? o0 : (blockIdx.z == 1 ? o1 : o2);
  __shared__ __align__(16) _Float16 lA[128 * 32];
  __shared__ __align__(16) _Float16 lB[128 * 32];
  int t = threadIdx.x, lane = t & 63, w = t >> 6;
  int l15 = lane & 15, g = lane >> 4;
  int wr = w >> 1, wc = w & 1;
  int m0 = blockIdx.x * 128, n0 = blockIdx.y * 128;
  f4 zed = {0.f, 0.f, 0.f, 0.f};
  f4 acc[4][4];
  for (int i = 0; i < 4; ++i)
    for (int j = 0; j < 4; ++j) acc[i][j] = zed;

  int row = t >> 2, colh = (t & 3) * 8;
  const _Float16* ga = A + (size_t)(m0 + row) * DM + colh;
  const _Float16* gb = Bt + (size_t)(n0 + row) * DM + colh;
  _Float16* la0 = &lA[row * 32 + colh];
  _Float16* la1 = &lA[2048 + row * 32 + colh];
  _Float16* lb0 = &lB[row * 32 + colh];
  _Float16* lb1 = &lB[2048 + row * 32 + colh];

  for (int k0 = 0; k0 < DM; k0 += 32) {
    __syncthreads();
    gload16(ga + k0, la0);
    gload16(ga + (size_t)64 * DM + k0, la1);
    gload16(gb + k0, lb0);
    gload16(gb + (size_t)64 * DM + k0, lb1);
    __syncthreads();
    h8 af[4], bfr[4];
#pragma unroll
    for (int mr = 0; mr < 4; ++mr)
      af[mr] = *(const h8*)&lA[(wr * 64 + mr * 16 + l15) * 32 + g * 8];
#pragma unroll
    for (int nr = 0; nr < 4; ++nr)
      bfr[nr] = *(const h8*)&lB[(wc * 64 + nr * 16 + l15) * 32 + g * 8];
#pragma unroll
    for (int mr = 0; mr < 4; ++mr)
#pragma unroll
      for (int nr = 0; nr < 4; ++nr)
        acc[mr][nr] = __builtin_amdgcn_mfma_f32_16x16x32_f16(af[mr], bfr[nr],
                                                             acc[mr][nr], 0, 0, 0);
  }

  if (mode == 0) {
    _Float16* o = (_Float16*)out;
#pragma unroll
    for (int mr = 0; mr < 4; ++mr)
#pragma unroll
      for (int nr = 0; nr < 4; ++nr) {
        int n = n0 + wc * 64 + nr * 16 + l15;
        int h = n >> 6, dk = n & 63;
#pragma unroll
        for (int r = 0; r < 4; ++r) {
          int m = m0 + wr * 64 + mr * 16 + g * 4 + r;
          int b = m >> 11, l = m & 2047;
          o[(((size_t)b * NH + h) * L_SEQ + l) * DKH + dk] = (_Float16)acc[mr][nr][r];
        }
      }
  } else {
    float* o = (float*)out;
#pragma unroll
    for (int mr = 0; mr < 4; ++mr)
#pragma unroll
      for (int nr = 0; nr < 4; ++nr) {
        int n = n0 + wc * 64 + nr * 16 + l15;
#pragma unroll
        for (int r = 0; r < 4; ++r) {
          int m = m0 + wr * 64 + mr * 16 + g * 4 + r;
          o[(size_t)m * DM + n] = acc[mr][nr][r];
        }
      }
  }
}

// ------------- attention -------------
// Grid 512 = 32 bh x 16 pairs; bh = blk & 31 (constant XCD per head),
// pair = blk >> 5. Complement pairing: sub-tile a = q-tile pair (tA), sub-tile
// b = q-tile 31-pair (tB). Each of 4 waves owns rows w*16..w*16+15 of BOTH
// tiles -> per-wave compute is constant (33 sub-chunks), zero-fill constant.
// K and V chunk fragments are shared by a and b while cc <= tA.
// Q pre-scaled by log2(e)/8 (k_wt) -> S in exp2 domain. A + zero-fill use
// nontemporal stores so the 537MB A stream doesn't evict K/V from L2.
__global__ __launch_bounds__(256, 2) void k_attn(const _Float16* __restrict__ Qh,
                                                 const _Float16* __restrict__ Kh,
                                                 const _Float16* __restrict__ Vt,
                                                 float* __restrict__ Aout,
                                                 _Float16* __restrict__ Oh) {
  __shared__ __align__(16) _Float16 Plds[4][2][1024];  // 2KB per wave per sub-tile
  const int blk = blockIdx.x;
  const int bh = blk & 31;
  const int pair = blk >> 5;
  const int tA = pair, tB = 31 - pair;  // tA < tB always
  const int b = bh >> 4, h = bh & 15;
  const int t = threadIdx.x, w = t >> 6, lane = t & 63;
  const int l15 = lane & 15, g = lane >> 4;
  const int q0a = tA * 64 + w * 16;  // sub-tile a rows: q0a..q0a+15
  const int q0b = tB * 64 + w * 16;  // sub-tile b rows
  const int qa = q0a + l15;
  const int qb = q0b + l15;

  const _Float16* Qpa = Qh + ((size_t)bh * L_SEQ + qa) * DKH + g * 8;
  const _Float16* Qpb = Qh + ((size_t)bh * L_SEQ + qb) * DKH + g * 8;
  const h8 qa0 = *(const h8*)Qpa;
  const h8 qa1 = *(const h8*)(Qpa + 32);
  const h8 qb0 = *(const h8*)Qpb;
  const h8 qb1 = *(const h8*)(Qpb + 32);
  const _Float16* Kbase = Kh + (size_t)bh * L_SEQ * DKH;
  const _Float16* Vbase = Vt + (size_t)bh * DKH * L_SEQ;
  float* Abase = Aout + (size_t)bh * L_SEQ * L_SEQ;
  char* pA = (char*)&Plds[w][0][0];
  char* pB = (char*)&Plds[w][1][0];
  const int swz = (l15 & 7) << 4;

  f4 zed = {0.f, 0.f, 0.f, 0.f};

  // ---- pass 1: per-row sum of exp2(sv) and max(sv) ----
  float mA = -1e30f, sumA = 0.f, mB = -1e30f, sumB = 0.f;
  for (int cc = 0; cc <= tB; ++cc) {
    const _Float16* Kp = Kbase + (size_t)(cc * 64 + l15) * DKH + g * 8;
    h8 kf0[4], kf1[4];
#pragma unroll
    for (int tt = 0; tt < 4; ++tt) {
      kf0[tt] = *(const h8*)(Kp + (size_t)tt * 16 * DKH);
      kf1[tt] = *(const h8*)(Kp + (size_t)tt * 16 * DKH + 32);
    }
    const bool doA = (cc <= tA);
    const bool dA = (cc == tA), dB = (cc == tB);
    f4 sa[4], sb[4];
    __builtin_amdgcn_s_setprio(1);
#pragma unroll
    for (int tt = 0; tt < 4; ++tt) {
      sb[tt] = __builtin_amdgcn_mfma_f32_16x16x32_f16(kf0[tt], qb0, zed, 0, 0, 0);
      sb[tt] = __builtin_amdgcn_mfma_f32_16x16x32_f16(kf1[tt], qb1, sb[tt], 0, 0, 0);
    }
    if (doA) {
#pragma unroll
      for (int tt = 0; tt < 4; ++tt) {
        sa[tt] = __builtin_amdgcn_mfma_f32_16x16x32_f16(kf0[tt], qa0, zed, 0, 0, 0);
        sa[tt] = __builtin_amdgcn_mfma_f32_16x16x32_f16(kf1[tt], qa1, sa[tt], 0, 0, 0);
      }
    }
    __builtin_amdgcn_s_setprio(0);
#pragma unroll
    for (int tt = 0; tt < 4; ++tt) {
      int kb = cc * 64 + tt * 16 + g * 4;
#pragma unroll
      for (int r = 0; r < 4; ++r) {
        float vb = (!dB || kb + r <= qb) ? sb[tt][r] : -1e30f;
        mB = fmaxf(mB, vb);
        sumB += __builtin_amdgcn_exp2f(vb);
      }
      if (doA) {
#pragma unroll
        for (int r = 0; r < 4; ++r) {
          float va = (!dA || kb + r <= qa) ? sa[tt][r] : -1e30f;
          mA = fmaxf(mA, va);
          sumA += __builtin_amdgcn_exp2f(va);
        }
      }
    }
  }
  // reduce over the 4 lanes sharing each q-row (l15, +16, +32, +48)
  mA = fmaxf(mA, __shfl_xor(mA, 16, 64));
  sumA += __shfl_xor(sumA, 16, 64);
  mA = fmaxf(mA, __shfl_xor(mA, 32, 64));
  sumA += __shfl_xor(sumA, 32, 64);
  mB = fmaxf(mB, __shfl_xor(mB, 16, 64));
  sumB += __shfl_xor(sumB, 16, 64);
  mB = fmaxf(mB, __shfl_xor(mB, 32, 64));
  sumB += __shfl_xor(sumB, 32, 64);
  const float cA = fmaxf(mA - 12.f, 0.f);  // f16 guard: P = exp2(sv-c) <= 4096
  const float cB = fmaxf(mB - 12.f, 0.f);
  const float invA = __builtin_amdgcn_exp2f(cA) / sumA;
  const float invB = __builtin_amdgcn_exp2f(cB) / sumB;

  // ---- pass 2: recompute S, write A = exp2(sv-c)*inv (nt), accumulate O ----
  f4 oaccA[4], oaccB[4];
#pragma unroll
  for (int dt = 0; dt < 4; ++dt) { oaccA[dt] = zed; oaccB[dt] = zed; }

  for (int cc = 0; cc <= tB; ++cc) {
    const _Float16* Kp = Kbase + (size_t)(cc * 64 + l15) * DKH + g * 8;
    h8 kf0[4], kf1[4];
#pragma unroll
    for (int tt = 0; tt < 4; ++tt) {
      kf0[tt] = *(const h8*)(Kp + (size_t)tt * 16 * DKH);
      kf1[tt] = *(const h8*)(Kp + (size_t)tt * 16 * DKH + 32);
    }
    const bool doA = (cc <= tA);
    const bool dA = (cc == tA), dB = (cc == tB);
    f4 sa[4], sb[4];
    __builtin_amdgcn_s_setprio(1);
#pragma unroll
    for (int tt = 0; tt < 4; ++tt) {
      sb[tt] = __builtin_amdgcn_mfma_f32_16x16x32_f16(kf0[tt], qb0, zed, 0, 0, 0);
      sb[tt] = __builtin_amdgcn_mfma_f32_16x16x32_f16(kf1[tt], qb1, sb[tt], 0, 0, 0);
    }
    if (doA) {
#pragma unroll
      for (int tt = 0; tt < 4; ++tt) {
        sa[tt] = __builtin_amdgcn_mfma_f32_16x16x32_f16(kf0[tt], qa0, zed, 0, 0, 0);
        sa[tt] = __builtin_amdgcn_mfma_f32_16x16x32_f16(kf1[tt], qa1, sa[tt], 0, 0, 0);
      }
    }
    __builtin_amdgcn_s_setprio(0);

    // V loads issued here: K-frags are dead (regs free) and the softmax VALU
    // block below hides the L2 latency. Shared by both sub-tiles.
    const _Float16* Vp = Vbase + (size_t)l15 * L_SEQ + cc * 64 + g * 8;
    h8 vf[8];
#pragma unroll
    for (int ks = 0; ks < 2; ++ks)
#pragma unroll
      for (int dt = 0; dt < 4; ++dt)
        vf[ks * 4 + dt] = *(const h8*)(Vp + (size_t)dt * 16 * L_SEQ + ks * 32);

    float* ArowB = Abase + (size_t)qb * L_SEQ + cc * 64 + g * 4;
#pragma unroll
    for (int tt = 0; tt < 4; ++tt) {
      f4 pv;
#pragma unroll
      for (int r = 0; r < 4; ++r) {
        float sv = sb[tt][r] - cB;
        if (dB && (cc * 64 + tt * 16 + g * 4 + r > qb)) sv = -1e30f;
        pv[r] = __builtin_amdgcn_exp2f(sv);
      }
      f4 av = {pv[0] * invB, pv[1] * invB, pv[2] * invB, pv[3] * invB};
      __builtin_nontemporal_store(av, (f4*)(ArowB + tt * 16));
      h4 ph = {(_Float16)pv[0], (_Float16)pv[1], (_Float16)pv[2], (_Float16)pv[3]};
      *(h4*)(pB + l15 * 128 + ((tt * 32 + g * 8) ^ swz)) = ph;
    }
    if (doA) {
      float* ArowA = Abase + (size_t)qa * L_SEQ + cc * 64 + g * 4;
#pragma unroll
      for (int tt = 0; tt < 4; ++tt) {
        f4 pv;
#pragma unroll
        for (int r = 0; r < 4; ++r) {
          float sv = sa[tt][r] - cA;
          if (dA && (cc * 64 + tt * 16 + g * 4 + r > qa)) sv = -1e30f;
          pv[r] = __builtin_amdgcn_exp2f(sv);
        }
        f4 av = {pv[0] * invA, pv[1] * invA, pv[2] * invA, pv[3] * invA};
        __builtin_nontemporal_store(av, (f4*)(ArowA + tt * 16));
        h4 ph = {(_Float16)pv[0], (_Float16)pv[1], (_Float16)pv[2], (_Float16)pv[3]};
        *(h4*)(pA + l15 * 128 + ((tt * 32 + g * 8) ^ swz)) = ph;
      }
    }
    asm volatile("s_waitcnt lgkmcnt(0)" ::: "memory");
    __builtin_amdgcn_sched_barrier(0);
    __builtin_amdgcn_s_setprio(1);
#pragma unroll
    for (int ks = 0; ks < 2; ++ks) {
      h8 pfb = *(const h8*)(pB + l15 * 128 + ((ks * 64 + g * 16) ^ swz));
#pragma unroll
      for (int dt = 0; dt < 4; ++dt)
        oaccB[dt] = __builtin_amdgcn_mfma_f32_16x16x32_f16(pfb, vf[ks * 4 + dt],
                                                           oaccB[dt], 0, 0, 0);
    }
    if (doA) {
#pragma unroll
      for (int ks = 0; ks < 2; ++ks) {
        h8 pfa = *(const h8*)(pA + l15 * 128 + ((ks * 64 + g * 16) ^ swz));
#pragma unroll
        for (int dt = 0; dt < 4; ++dt)
          oaccA[dt] = __builtin_amdgcn_mfma_f32_16x16x32_f16(pfa, vf[ks * 4 + dt],
                                                             oaccA[dt], 0, 0, 0);
      }
    }
    __builtin_amdgcn_s_setprio(0);
  }

  // O write (f16, [B][L][D]); O rows live at q = g*4+r (C-layout), so fetch
  // that row's scale from the lane that owns it (lane g*4+r has l15 == g*4+r).
  float scA[4], scB[4];
#pragma unroll
  for (int r = 0; r < 4; ++r) {
    scA[r] = __shfl(invA, g * 4 + r, 64);
    scB[r] = __shfl(invB, g * 4 + r, 64);
  }
#pragma unroll
  for (int dt = 0; dt < 4; ++dt)
#pragma unroll
    for (int r = 0; r < 4; ++r) {
      Oh[((size_t)b * L_SEQ + q0a + g * 4 + r) * DM + h * DKH + dt * 16 + l15] =
          (_Float16)(oaccA[dt][r] * scA[r]);
      Oh[((size_t)b * L_SEQ + q0b + g * 4 + r) * DM + h * DKH + dt * 16 + l15] =
          (_Float16)(oaccB[dt][r] * scB[r]);
    }

  // zero-fill strictly-masked columns beyond each diagonal chunk (nt stores).
  // Combined length is constant across pairs -> balanced.
  const int zsA = (tA + 1) * 64, zsB = (tB + 1) * 64;
  for (int rr = 0; rr < 16; ++rr) {
    float* p = Abase + (size_t)(q0a + rr) * L_SEQ;
    for (int cz = zsA + lane * 4; cz < L_SEQ; cz += 256)
      __builtin_nontemporal_store(zed, (f4*)(p + cz));
  }
  for (int rr = 0; rr < 16; ++rr) {
    float* p = Abase + (size_t)(q0b + rr) * L_SEQ;
    for (int cz = zsB + lane * 4; cz < L_SEQ; cz += 256)
      __builtin_nontemporal_store(zed, (f4*)(p + cz));
  }
}

extern "C" void kernel_launch(void* const* d_in, const int* in_sizes, int n_in,
                              void* d_out, int out_size, void* d_ws, size_t ws_size,
                              hipStream_t stream) {
  const float* query = (const float*)d_in[0];
  // d_in[1] = causal mask (constant triu k=1) — recomputed in-kernel, unused.
  const float* Wq = (const float*)d_in[2];
  const float* Wk = (const float*)d_in[3];
  const float* Wv = (const float*)d_in[4];
  const float* Wo = (const float*)d_in[5];

  char* ws = (char*)d_ws;
  _Float16* qh  = (_Float16*)(ws);                      //  8 MB  [4096][1024]
  _Float16* Wtq = (_Float16*)(ws + (8ull  << 20));      //  2 MB  [1024][1024]
  _Float16* Wtk = (_Float16*)(ws + (10ull << 20));
  _Float16* Wtv = (_Float16*)(ws + (12ull << 20));
  _Float16* Wto = (_Float16*)(ws + (14ull << 20));
  _Float16* Qh  = (_Float16*)(ws + (16ull << 20));      //  8 MB  [bh][L][64]
  _Float16* Kh  = (_Float16*)(ws + (24ull << 20));
  _Float16* Vh  = (_Float16*)(ws + (32ull << 20));
  _Float16* Vtr = (_Float16*)(ws + (40ull << 20));      //  8 MB  [bh][64][L]
  _Float16* Oh  = (_Float16*)(ws + (48ull << 20));      //  8 MB  [4096][1024]

  float* y = (float*)d_out;
  float* Afull = y + (size_t)4194304;

  k_cast<<<4096, 256, 0, stream>>>(query, qh, 1048576);
  k_wt<<<dim3(16, 16, 4), 256, 0, stream>>>(Wq, Wk, Wv, Wo, Wtq, Wtk, Wtv, Wto);
  k_gemm<<<dim3(32, 8, 3), 256, 0, stream>>>(qh, Wtq, Wtk, Wtv, Qh, Kh, Vh, 0);
  k_vt<<<1024, 256, 0, stream>>>(Vh, Vtr);
  k_attn<<<512, 256, 0, stream>>>(Qh, Kh, Vtr, Afull, Oh);
  k_gemm<<<dim3(32, 8, 1), 256, 0, stream>>>(Oh, Wto, Wto, Wto, y, y, y, 1);
}